// Round 9
// baseline (131.647 us; speedup 1.0000x reference)
//
#include <hip/hip_runtime.h>
#include <hip/hip_bf16.h>
#include <math.h>

#define NB 4
#define NC 50
#define NN 4096

typedef __attribute__((ext_vector_type(8))) short short8;
typedef __attribute__((ext_vector_type(4))) float f32x4;

static constexpr float F_SCALE = 0.14142135623730951f;  // 50^-0.5
static constexpr float F_LOG2E = 1.44269504088896340f;  // exp(x)=exp2(x*log2e), folded into qb
static constexpr float F_DT = 0.001f;

// ---- workspace layout (f32 units) ----
static constexpr size_t OFF_XP  = 0;                                   // xpad [4][66][68][64] bf16
static constexpr size_t SZ_XP   = (size_t)4*66*68*64/2;
static constexpr size_t OFF_W1T = OFF_XP + SZ_XP;                      // w1t2 [3][50ks][64oc][32] bf16
static constexpr size_t SZ_W1T  = (size_t)3*25*64*64/2;
static constexpr size_t OFF_BI  = OFF_W1T + SZ_W1T;                    // bias [3][64] f32
static constexpr size_t SZ_BI   = 192;
static constexpr size_t OFF_W2T = OFF_BI + SZ_BI;                      // w2t2 [3][8ks][64oc][32] bf16
static constexpr size_t SZ_W2T  = (size_t)3*4*64*64/2;
static constexpr size_t OFF_T1P = OFF_W2T + SZ_W2T;                    // t1pad [12][66][66][64] bf16
static constexpr size_t SZ_T1P  = (size_t)12*66*66*64/2;
static constexpr size_t OFF_QB  = OFF_T1P + SZ_T1P;                    // qb [4][4096][64] bf16 (scaled*log2e)
static constexpr size_t SZ_QB   = (size_t)4*NN*64/2;
static constexpr size_t OFF_KB  = OFF_QB + SZ_QB;
static constexpr size_t SZ_KB   = SZ_QB;
static constexpr size_t OFF_VV  = OFF_KB + SZ_KB;                      // vv [4][4096][64] f32
static constexpr size_t SZ_VV   = (size_t)4*NN*64;
static constexpr size_t OFF_LP  = OFF_VV + SZ_VV;                      // Lpart [8][16384]
static constexpr size_t SZ_LP   = (size_t)8*NB*NN;
static constexpr size_t OFF_MP  = OFF_LP + SZ_LP;                      // Mpart [8][16384]
static constexpr size_t SZ_MP   = (size_t)8*NB*NN;
static constexpr size_t OFF_L   = OFF_MP + SZ_MP;                      // L [16384]
static constexpr size_t SZ_L    = (size_t)NB*NN;
static constexpr size_t OFF_GT  = OFF_L + SZ_L;                        // gateL [1]
static constexpr size_t OFF_QN2 = OFF_GT + 1;                          // qnorm2 [16384]
static constexpr size_t SZ_QN2  = (size_t)NB*NN;
static constexpr size_t OFF_KMX = OFF_QN2 + SZ_QN2;                    // kmax2 bits [1]
static constexpr size_t OFF_GN  = OFF_KMX + 1;                         // gateN [1]
static constexpr size_t OFF_CNT = OFF_GN + 1;                          // block counter [1]

__device__ __forceinline__ float bf2f(short s) {
  return __uint_as_float(((unsigned)(unsigned short)s) << 16);
}

// async global->LDS DMA, 16B per lane; LDS dest = wave-uniform base + lane*16,
// global source is per-lane. (m97 mechanism: compiler can't sink past barrier.)
__device__ __forceinline__ void stage16(const void* g, void* l) {
  __builtin_amdgcn_global_load_lds(
      (const __attribute__((address_space(1))) unsigned*)g,
      (__attribute__((address_space(3))) unsigned*)l, 16, 0, 0);
}

// ---------------- P: merged prep — xpad build + weight prep + init (one dispatch) --
// blocks [0,4488): xpad; [4488,4575): weights; [4575,6911): t1p pad strips + out zero
__global__ __launch_bounds__(256) void k_prep(const float* __restrict__ x,
                                              const float* __restrict__ w1,
                                              const float* __restrict__ w2,
                                              const float* __restrict__ g,
                                              const float* __restrict__ be,
                                              const float* __restrict__ mu,
                                              const float* __restrict__ va,
                                              __hip_bfloat16* __restrict__ xp,
                                              __hip_bfloat16* __restrict__ w1t,
                                              float* __restrict__ bias,
                                              __hip_bfloat16* __restrict__ w2t,
                                              __hip_bfloat16* __restrict__ t1p,
                                              float* __restrict__ out,
                                              float* __restrict__ gateL,
                                              float* __restrict__ gateN,
                                              int* __restrict__ kmx,
                                              int* __restrict__ cnt) {
  int bx = blockIdx.x;
  int tid = threadIdx.x;
  if (bx == 0 && tid == 0) {
    gateL[0] = 0.f; gateN[0] = 0.f; kmx[0] = 0; cnt[0] = 0;
  }
  if (bx < 4488) {
    // ---- xpad[b][66][68][64]: xpad[b][h][w][c] = x[b][(h-2)*64+w][c] or 0 ----
    int pos = bx * 4 + (tid >> 6);
    int c = tid & 63;
    int b = pos / 4488;
    int rem = pos % 4488;
    int h = rem / 68, w = rem % 68;
    int y = h - 2;
    float v = 0.f;
    if (y >= 0 && y < 64 && w < 64 && c < NC)
      v = x[((size_t)b*NN + y*64 + w)*NC + c];
    xp[(size_t)pos*64 + c] = __float2bfloat16(v);
  } else if (bx < 4575) {
    int bw = bx - 4488;
    if (bw < 75) {
      int p = bw / 25, tap = bw % 25, dy = tap / 5, dx = tap % 5;
      for (int i = tid; i < 4096; i += 256) {
        int oc = i >> 6, c = i & 63;
        float v = 0.f;
        if (oc < NC && c < NC) {
          float sc = g[p*NC+oc] * rsqrtf(va[p*NC+oc] + 1e-5f);
          v = w1[(((size_t)p*NC + oc)*NC + c)*25 + tap] * sc;
        }
        int k = dx*64 + c;
        int ks = dy*10 + (k >> 5), ck = k & 31;
        w1t[(((size_t)p*50 + ks)*64 + oc)*32 + ck] = __float2bfloat16(v);
      }
      if (tap == 0 && tid < 64) {
        int oc = tid;
        float v = 0.f;
        if (oc < NC) {
          float sc = g[p*NC+oc] * rsqrtf(va[p*NC+oc] + 1e-5f);
          v = be[p*NC+oc] - mu[p*NC+oc]*sc;
        }
        bias[p*64 + oc] = v;
      }
    } else {
      int i2 = bw - 75;
      int p = i2 / 4, tap = i2 % 4, dy = tap >> 1, dx = tap & 1;
      for (int i = tid; i < 4096; i += 256) {
        int oc = i >> 6, c = i & 63;
        float v = 0.f;
        if (oc < NC && c < NC)
          v = w2[(((size_t)p*NC + oc)*NC + c)*4 + tap];
        int k = dx*64 + c;
        int ks = dy*4 + (k >> 5), ck = k & 31;
        w2t[(((size_t)p*8 + ks)*64 + oc)*32 + ck] = __float2bfloat16(v);
      }
    }
  } else {
    int bz = bx - 4575;
    if (bz < 1536) {
      int idx = bz * 256 + tid;              // 393216 t1pad pad elems
      int pb = idx >> 15, r = idx & 32767;
      int h2, w, c;
      if (r < 16896) {
        int hsel = r / 4224;
        h2 = hsel < 3 ? hsel : 65;
        int rem = r % 4224;
        w = rem >> 6; c = rem & 63;
      } else {
        int r2 = r - 16896;
        h2 = 3 + (r2 >> 8);
        int rem = r2 & 255;
        w = 62 + (rem >> 6); c = rem & 63;
      }
      t1p[(((size_t)pb*66 + h2)*66 + w)*64 + c] = __float2bfloat16(0.f);
    } else {
      int i = (bz - 1536) * 256 + tid;       // 204800 float4 = 819200 f32 of out
      float4 z = {0.f, 0.f, 0.f, 0.f};
      ((float4*)out)[i] = z;
    }
  }
}

// ---------------- C1: conv1 GEMM K=1600; LDS-staged A (once) + W (dbuf/kstep) -----
// grid (62 rows, 12 p*b), 4 waves; wave = 16px x 64oc.  [unchanged from R8]
__global__ __launch_bounds__(256, 3) void k_conv1m(const __hip_bfloat16* __restrict__ xp,
                                                   const __hip_bfloat16* __restrict__ w1t,
                                                   const float* __restrict__ bias,
                                                   __hip_bfloat16* __restrict__ t1p) {
  __shared__ char smem[45056 + 8192];
  char* als = smem;
  char* wls = smem + 45056;
  int tid = threadIdx.x;
  int w = tid >> 6, lane = tid & 63;
  int lr = lane & 15, lk = lane >> 4;
  int row = blockIdx.x;                        // output row 0..61
  int px0 = w * 16;
  int pb = blockIdx.y; int p = pb / 4, b = pb % 4;

  const char* awin = (const char*)xp + (((size_t)b*66 + row)*68) * 128;  // 5 rows x 8704 B
  const char* wsrc = (const char*)w1t + (size_t)p*50*4096;

#pragma unroll
  for (int it = 0; it < 11; ++it) {
    int L = it*4096 + tid*16;
    int PX = L >> 7;
    int slot = ((L >> 4) ^ PX) & 7;
    stage16(awin + PX*128 + slot*16, als + it*4096 + w*1024);
  }
  stage16(wsrc + tid*16, wls + w*1024);
  __syncthreads();                             // vmcnt(0) drain: A + W[0] ready

  f32x4 acc0 = {0.f,0.f,0.f,0.f}, acc1 = acc0, acc2 = acc0, acc3 = acc0;
  int fbase = (px0 + lr)*128 + lk*16;
  const char* wfb = wls + lr*64 + lk*16;

#pragma unroll
  for (int ks = 0; ks < 50; ++ks) {
    if (ks + 1 < 50)                           // async prefetch next W chunk
      stage16(wsrc + (ks+1)*4096 + tid*16, wls + ((ks+1)&1)*4096 + w*1024);
    int dy = ks / 10, kk = ks % 10;
    int F = dy*8704 + fbase + kk*64;           // flat A byte (unswizzled)
    int lb = (F & ~127) | ((((F>>4) ^ (F>>7)) & 7) << 4);
    short8 av = *(const short8*)(als + lb);
    const char* wc = wfb + (ks & 1)*4096;
    short8 wv0 = *(const short8*)(wc);
    short8 wv1 = *(const short8*)(wc + 1024);
    short8 wv2 = *(const short8*)(wc + 2048);
    short8 wv3 = *(const short8*)(wc + 3072);
    acc0 = __builtin_amdgcn_mfma_f32_16x16x32_bf16(av, wv0, acc0, 0, 0, 0);
    acc1 = __builtin_amdgcn_mfma_f32_16x16x32_bf16(av, wv1, acc1, 0, 0, 0);
    acc2 = __builtin_amdgcn_mfma_f32_16x16x32_bf16(av, wv2, acc2, 0, 0, 0);
    acc3 = __builtin_amdgcn_mfma_f32_16x16x32_bf16(av, wv3, acc3, 0, 0, 0);
    __syncthreads();                           // drain prefetch; protect buffer reuse
  }

  int h2 = row + 3;
  __hip_bfloat16* orow = t1p + (((size_t)(p*NB + b)*66 + h2)*66)*64;
  f32x4 accs[4] = {acc0, acc1, acc2, acc3};
#pragma unroll
  for (int nt = 0; nt < 4; ++nt) {
    float bv = bias[p*64 + nt*16 + lr];
#pragma unroll
    for (int r = 0; r < 4; ++r) {
      int j1 = px0 + lk*4 + r;
      float val = (j1 < 62) ? (accs[nt][r] + bv) : 0.f;
      orow[(size_t)j1*64 + nt*16 + lr] = __float2bfloat16(val);
    }
  }
}

// ---------------- C2: conv2 GEMM K=256 + gate epilogue (last-block pattern) -------
// grid (64 rows, 12 p*b), 4 waves. A = 2 t1p rows; all W staged once.
__global__ __launch_bounds__(256, 3) void k_conv2m(const __hip_bfloat16* __restrict__ t1p,
                                                   const __hip_bfloat16* __restrict__ w2t,
                                                   __hip_bfloat16* __restrict__ qb,
                                                   __hip_bfloat16* __restrict__ kb,
                                                   float* __restrict__ vv,
                                                   float* __restrict__ qn2,
                                                   int* __restrict__ kmx,
                                                   int* __restrict__ cnt,
                                                   float* __restrict__ gateN) {
  __shared__ char smem[20480 + 32768];
  char* als = smem;
  char* wls = smem + 20480;
  int tid = threadIdx.x;
  int w = tid >> 6, lane = tid & 63;
  int lr = lane & 15, lk = lane >> 4;
  int row = blockIdx.x;                        // output row 0..63
  int px0 = w * 16;
  int pb = blockIdx.y; int p = pb / 4, b = pb % 4;

  const char* awin = (const char*)t1p + (((size_t)(p*NB + b)*66 + row)*66) * 128; // 2 rows
  const char* wsrc = (const char*)w2t + (size_t)p*8*4096;

#pragma unroll
  for (int it = 0; it < 5; ++it) {
    int L = it*4096 + tid*16;
    int PX = L >> 7;
    int slot = ((L >> 4) ^ PX) & 7;
    stage16(awin + PX*128 + slot*16, als + it*4096 + w*1024);
  }
#pragma unroll
  for (int it = 0; it < 8; ++it)
    stage16(wsrc + it*4096 + tid*16, wls + it*4096 + w*1024);
  __syncthreads();                             // everything resident

  f32x4 acc0 = {0.f,0.f,0.f,0.f}, acc1 = acc0, acc2 = acc0, acc3 = acc0;
  int fbase = (px0 + lr)*128 + lk*16;
  const char* wfb = wls + lr*64 + lk*16;

#pragma unroll
  for (int ks = 0; ks < 8; ++ks) {
    int dy = ks >> 2, kk = ks & 3;
    int F = dy*8448 + fbase + kk*64;
    int lb = (F & ~127) | ((((F>>4) ^ (F>>7)) & 7) << 4);
    short8 av = *(const short8*)(als + lb);
    const char* wc = wfb + ks*4096;
    short8 wv0 = *(const short8*)(wc);
    short8 wv1 = *(const short8*)(wc + 1024);
    short8 wv2 = *(const short8*)(wc + 2048);
    short8 wv3 = *(const short8*)(wc + 3072);
    acc0 = __builtin_amdgcn_mfma_f32_16x16x32_bf16(av, wv0, acc0, 0, 0, 0);
    acc1 = __builtin_amdgcn_mfma_f32_16x16x32_bf16(av, wv1, acc1, 0, 0, 0);
    acc2 = __builtin_amdgcn_mfma_f32_16x16x32_bf16(av, wv2, acc2, 0, 0, 0);
    acc3 = __builtin_amdgcn_mfma_f32_16x16x32_bf16(av, wv3, acc3, 0, 0, 0);
  }

  f32x4 accs[4] = {acc0, acc1, acc2, acc3};
  if (p == 0) {
    float sq[4] = {0.f, 0.f, 0.f, 0.f};
#pragma unroll
    for (int nt = 0; nt < 4; ++nt) {
#pragma unroll
      for (int r = 0; r < 4; ++r) {
        int n = row*64 + px0 + lk*4 + r;
        __hip_bfloat16 qv = __float2bfloat16(accs[nt][r] * (F_SCALE * F_LOG2E));
        qb[((size_t)b*NN + n)*64 + nt*16 + lr] = qv;
        float a = bf2f(*(short*)&qv);
        sq[r] += a*a;
      }
    }
#pragma unroll
    for (int r = 0; r < 4; ++r) {
#pragma unroll
      for (int m = 1; m < 16; m <<= 1) sq[r] += __shfl_xor(sq[r], m, 64);
    }
    if (lr == 0) {
#pragma unroll
      for (int r = 0; r < 4; ++r)
        qn2[(size_t)b*NN + row*64 + px0 + lk*4 + r] = sq[r];
    }
  } else if (p == 1) {
    float sk[4] = {0.f, 0.f, 0.f, 0.f};
#pragma unroll
    for (int nt = 0; nt < 4; ++nt) {
#pragma unroll
      for (int r = 0; r < 4; ++r) {
        int n = row*64 + px0 + lk*4 + r;
        __hip_bfloat16 kv = __float2bfloat16(accs[nt][r]);
        kb[((size_t)b*NN + n)*64 + nt*16 + lr] = kv;
        float a = bf2f(*(short*)&kv);
        sk[r] += a*a;
      }
    }
    float mk = fmaxf(fmaxf(sk[0], sk[1]), fmaxf(sk[2], sk[3]));
#pragma unroll
    for (int m = 1; m < 64; m <<= 1) mk = fmaxf(mk, __shfl_xor(mk, m, 64));
    if (lane == 0) atomicMax(kmx, __float_as_int(mk));  // >=0: bit order == float order
  } else {
#pragma unroll
    for (int nt = 0; nt < 4; ++nt) {
#pragma unroll
      for (int r = 0; r < 4; ++r) {
        int n = row*64 + px0 + lk*4 + r;
        vv[((size_t)b*NN + n)*64 + nt*16 + lr] = accs[nt][r];
      }
    }
  }

  // ---- last-block gate: gateN = sum_t exp2(2*|q~_t|*Kmax)/N (sound col-mass UB) --
  __threadfence();                             // release qn2/kmx device-wide
  __shared__ int lastBlk;
  if (tid == 0) {
    int c = atomicAdd(cnt, 1);
    lastBlk = (c == 64*12 - 1);
  }
  __syncthreads();
  if (!lastBlk) return;
  __threadfence();                             // acquire
  float km = sqrtf(__int_as_float(kmx[0]));
  float part = 0.f;
  const float4* q4 = (const float4*)qn2;
  for (int i = tid; i < NB*NN/4; i += 256) {
    float4 v = q4[i];
    part += exp2f(2.f*sqrtf(v.x)*km) + exp2f(2.f*sqrtf(v.y)*km)
          + exp2f(2.f*sqrtf(v.z)*km) + exp2f(2.f*sqrtf(v.w)*km);
  }
  __shared__ float red[256];
  red[tid] = part;
  __syncthreads();
  for (int s = 128; s > 0; s >>= 1) {
    if (tid < s) red[tid] += red[tid + s];
    __syncthreads();
  }
  if (tid == 0) gateN[0] = red[0] * (1.f / (float)NN);
}

// ---------------- K3: MFMA row sums + row max (only if norm gate fails) -----------
__global__ __launch_bounds__(256) void k_L(const __hip_bfloat16* __restrict__ qb,
                                           const __hip_bfloat16* __restrict__ kb,
                                           const float* __restrict__ gateN,
                                           float* __restrict__ Lpart,
                                           float* __restrict__ Mpart) {
  if (F_DT * gateN[0] < 0.99f) return;    // provably no spikes -> L never consumed
  int w = threadIdx.x >> 6, lane = threadIdx.x & 63;
  int b = blockIdx.z, jc = blockIdx.y;
  int t0 = blockIdx.x * 64 + w * 16;
  int lr = lane & 15, lk = lane >> 4;

  const short* qrow = (const short*)qb + ((size_t)b*NN + t0 + lr)*64 + lk*8;
  short8 a0 = *(const short8*)qrow;
  short8 a1 = *(const short8*)(qrow + 32);
  const short* kp = (const short*)kb + ((size_t)b*NN + jc*512 + lr)*64 + lk*8;

  short8 n00 = *(const short8*)kp;
  short8 n01 = *(const short8*)(kp + 32);
  short8 n10 = *(const short8*)(kp + 1024);
  short8 n11 = *(const short8*)(kp + 1024 + 32);

  float rs[4] = {0.f, 0.f, 0.f, 0.f};
  float mx[4] = {-3e38f, -3e38f, -3e38f, -3e38f};
#pragma unroll 2
  for (int j = 0; j < 512; j += 32) {
    short8 b00 = n00, b01 = n01, b10 = n10, b11 = n11;
    kp += 32*64;
    if (j + 32 < 512) {
      n00 = *(const short8*)kp;
      n01 = *(const short8*)(kp + 32);
      n10 = *(const short8*)(kp + 1024);
      n11 = *(const short8*)(kp + 1024 + 32);
    }
    f32x4 d0 = {0.f,0.f,0.f,0.f}, d1 = {0.f,0.f,0.f,0.f};
    d0 = __builtin_amdgcn_mfma_f32_16x16x32_bf16(a0, b00, d0, 0, 0, 0);
    d0 = __builtin_amdgcn_mfma_f32_16x16x32_bf16(a1, b01, d0, 0, 0, 0);
    d1 = __builtin_amdgcn_mfma_f32_16x16x32_bf16(a0, b10, d1, 0, 0, 0);
    d1 = __builtin_amdgcn_mfma_f32_16x16x32_bf16(a1, b11, d1, 0, 0, 0);
#pragma unroll
    for (int r = 0; r < 4; ++r) {
      rs[r] += exp2f(d0[r]) + exp2f(d1[r]);
      mx[r] = fmaxf(mx[r], fmaxf(d0[r], d1[r]));
    }
  }
#pragma unroll
  for (int r = 0; r < 4; ++r) {
#pragma unroll
    for (int m = 1; m < 16; m <<= 1) {
      rs[r] += __shfl_xor(rs[r], m, 64);
      mx[r] = fmaxf(mx[r], __shfl_xor(mx[r], m, 64));
    }
  }
  if (lr == 0) {
    size_t base = (size_t)jc*(NB*NN) + (size_t)b*NN + t0 + lk*4;
#pragma unroll
    for (int r = 0; r < 4; ++r) {
      Lpart[base + r] = rs[r];
      Mpart[base + r] = mx[r];
    }
  }
}

// ---------------- K3b: reduce L, M; gateL = sum_t exp2(M_t)/L_t -------------------
__global__ __launch_bounds__(256) void k_Lred(const float* __restrict__ Lpart,
                                              const float* __restrict__ Mpart,
                                              const float* __restrict__ gateN,
                                              float* __restrict__ L,
                                              float* __restrict__ gateL) {
  if (F_DT * gateN[0] < 0.99f) return;
  int i = blockIdx.x * 256 + threadIdx.x;   // 16384
  float sum = 0.f, mx = -3e38f;
#pragma unroll
  for (int jc = 0; jc < 8; ++jc) {
    sum += Lpart[(size_t)jc*(NB*NN) + i];
    mx = fmaxf(mx, Mpart[(size_t)jc*(NB*NN) + i]);
  }
  L[i] = sum;
  float m = exp2f(mx) / sum;
  __shared__ float red[256];
  red[threadIdx.x] = m;
  __syncthreads();
  for (int s = 128; s > 0; s >>= 1) {
    if (threadIdx.x < s) red[threadIdx.x] += red[threadIdx.x + s];
    __syncthreads();
  }
  if (threadIdx.x == 0) atomicAdd(gateL, red[0]);
}

// ---------------- K5: spike fallback (exact serial walk; doubly gated) ------------
__global__ __launch_bounds__(256) void k_spike_fb(const __hip_bfloat16* __restrict__ qb,
                                                  const __hip_bfloat16* __restrict__ kb,
                                                  const float* __restrict__ L,
                                                  const float* __restrict__ gateN,
                                                  const float* __restrict__ gateL,
                                                  const float* __restrict__ vv,
                                                  float* __restrict__ out) {
  if (F_DT * gateN[0] < 0.99f) return;    // cheap bound says no spikes
  if (F_DT * gateL[0] < 0.99f) return;    // tight bound says no spikes
  int j = blockIdx.x * 256 + threadIdx.x;
  int b = blockIdx.y;

  float kf[64];
  const __hip_bfloat16* kr = kb + ((size_t)b*NN + j)*64;
#pragma unroll
  for (int c = 0; c < 64; ++c) kf[c] = __bfloat162float(kr[c]);
  const __hip_bfloat16* Qb = qb + (size_t)b*NN*64;
  const float* Lb = L + (size_t)b*NN;
  const float* V  = vv + ((size_t)b*NN + j)*64;

  float cum = 0.f, Fprev = 0.f;
  for (int t = 0; t < NN; ++t) {
    const __hip_bfloat16* qr = Qb + (size_t)t*64;
    float dot = 0.f;
    for (int c = 0; c < 64; ++c) dot += __bfloat162float(qr[c]) * kf[c];
    float r = exp2f(dot) / Lb[t];
    cum += r * F_DT;
    float F = floorf(cum);
    if (F > Fprev) {
      float sv = (F - Fprev) / F_DT;
      float* orow = out + ((size_t)b*NN + t)*NC;
      for (int d = 0; d < NC; ++d) atomicAdd(orow + d, sv * V[d]);
      Fprev = F;
    }
  }
}

extern "C" void kernel_launch(void* const* d_in, const int* in_sizes, int n_in,
                              void* d_out, int out_size, void* d_ws, size_t ws_size,
                              hipStream_t stream) {
  const float* x  = (const float*)d_in[0];
  const float* w1 = (const float*)d_in[1];
  const float* w2 = (const float*)d_in[2];
  const float* g  = (const float*)d_in[3];
  const float* be = (const float*)d_in[4];
  const float* mu = (const float*)d_in[5];
  const float* va = (const float*)d_in[6];
  float* out = (float*)d_out;
  float* ws  = (float*)d_ws;

  __hip_bfloat16* xp  = (__hip_bfloat16*)(ws + OFF_XP);
  __hip_bfloat16* w1t = (__hip_bfloat16*)(ws + OFF_W1T);
  float*          bi  = ws + OFF_BI;
  __hip_bfloat16* w2t = (__hip_bfloat16*)(ws + OFF_W2T);
  __hip_bfloat16* t1p = (__hip_bfloat16*)(ws + OFF_T1P);
  __hip_bfloat16* qb  = (__hip_bfloat16*)(ws + OFF_QB);
  __hip_bfloat16* kb  = (__hip_bfloat16*)(ws + OFF_KB);
  float* vv  = ws + OFF_VV;
  float* Lp  = ws + OFF_LP;
  float* Mp  = ws + OFF_MP;
  float* L   = ws + OFF_L;
  float* gtL = ws + OFF_GT;
  float* qn2 = ws + OFF_QN2;
  int*   kmx = (int*)(ws + OFF_KMX);
  float* gtN = ws + OFF_GN;
  int*   cnt = (int*)(ws + OFF_CNT);

  k_prep  <<<dim3(6911), dim3(256), 0, stream>>>(x, w1, w2, g, be, mu, va,
                                                 xp, w1t, bi, w2t, t1p, out,
                                                 gtL, gtN, kmx, cnt);
  k_conv1m<<<dim3(62, 12), dim3(256), 0, stream>>>(xp, w1t, bi, t1p);
  k_conv2m<<<dim3(64, 12), dim3(256), 0, stream>>>(t1p, w2t, qb, kb, vv, qn2, kmx, cnt, gtN);
  k_L     <<<dim3(64, 8, NB), dim3(256), 0, stream>>>(qb, kb, gtN, Lp, Mp);
  k_Lred  <<<dim3(64), dim3(256), 0, stream>>>(Lp, Mp, gtN, L, gtL);
  k_spike_fb<<<dim3(16, NB), dim3(256), 0, stream>>>(qb, kb, L, gtN, gtL, vv, out);
}

// Round 10
// 59.521 us; speedup vs baseline: 2.2118x; 2.2118x over previous
//
#include <hip/hip_runtime.h>
#include <hip/hip_bf16.h>
#include <math.h>

#define NB 4
#define NC 50
#define NN 4096

typedef __attribute__((ext_vector_type(8))) short short8;
typedef __attribute__((ext_vector_type(4))) float f32x4;

static constexpr float F_SCALE = 0.14142135623730951f;  // 50^-0.5
static constexpr float F_LOG2E = 1.44269504088896340f;  // exp(x)=exp2(x*log2e), folded into qb
static constexpr float F_DT = 0.001f;

// ---- workspace layout (f32 units) ----
static constexpr size_t OFF_XP  = 0;                                   // xpad [4][66][68][64] bf16
static constexpr size_t SZ_XP   = (size_t)4*66*68*64/2;
static constexpr size_t OFF_W1T = OFF_XP + SZ_XP;                      // w1t2 [3][50ks][64oc][32] bf16
static constexpr size_t SZ_W1T  = (size_t)3*25*64*64/2;
static constexpr size_t OFF_BI  = OFF_W1T + SZ_W1T;                    // bias [3][64] f32
static constexpr size_t SZ_BI   = 192;
static constexpr size_t OFF_W2T = OFF_BI + SZ_BI;                      // w2t2 [3][8ks][64oc][32] bf16
static constexpr size_t SZ_W2T  = (size_t)3*4*64*64/2;
static constexpr size_t OFF_T1P = OFF_W2T + SZ_W2T;                    // t1pad [12][66][66][64] bf16
static constexpr size_t SZ_T1P  = (size_t)12*66*66*64/2;
static constexpr size_t OFF_QB  = OFF_T1P + SZ_T1P;                    // qb [4][4096][64] bf16 (scaled*log2e)
static constexpr size_t SZ_QB   = (size_t)4*NN*64/2;
static constexpr size_t OFF_KB  = OFF_QB + SZ_QB;
static constexpr size_t SZ_KB   = SZ_QB;
static constexpr size_t OFF_VV  = OFF_KB + SZ_KB;                      // vv [4][4096][64] f32
static constexpr size_t SZ_VV   = (size_t)4*NN*64;
static constexpr size_t OFF_LP  = OFF_VV + SZ_VV;                      // Lpart [8][16384]
static constexpr size_t SZ_LP   = (size_t)8*NB*NN;
static constexpr size_t OFF_MP  = OFF_LP + SZ_LP;                      // Mpart [8][16384]
static constexpr size_t SZ_MP   = (size_t)8*NB*NN;
static constexpr size_t OFF_L   = OFF_MP + SZ_MP;                      // L [16384]
static constexpr size_t SZ_L    = (size_t)NB*NN;
static constexpr size_t OFF_GT  = OFF_L + SZ_L;                        // gateL [1]
static constexpr size_t OFF_QN2 = OFF_GT + 1;                          // qnorm2 [16384]
static constexpr size_t SZ_QN2  = (size_t)NB*NN;
static constexpr size_t OFF_KMX = OFF_QN2 + SZ_QN2;                    // kmax2 bits [1]
static constexpr size_t OFF_GN  = OFF_KMX + 1;                         // gateN [1]

__device__ __forceinline__ float bf2f(short s) {
  return __uint_as_float(((unsigned)(unsigned short)s) << 16);
}

// async global->LDS DMA, 16B per lane; LDS dest = wave-uniform base + lane*16,
// global source is per-lane. (m97 mechanism: compiler can't sink past barrier.)
__device__ __forceinline__ void stage16(const void* g, void* l) {
  __builtin_amdgcn_global_load_lds(
      (const __attribute__((address_space(1))) unsigned*)g,
      (__attribute__((address_space(3))) unsigned*)l, 16, 0, 0);
}

// ---------------- P: merged prep — xpad build + weight prep + init (one dispatch) --
// blocks [0,4488): xpad; [4488,4575): weights; [4575,6911): t1p pad strips + out zero
__global__ __launch_bounds__(256) void k_prep(const float* __restrict__ x,
                                              const float* __restrict__ w1,
                                              const float* __restrict__ w2,
                                              const float* __restrict__ g,
                                              const float* __restrict__ be,
                                              const float* __restrict__ mu,
                                              const float* __restrict__ va,
                                              __hip_bfloat16* __restrict__ xp,
                                              __hip_bfloat16* __restrict__ w1t,
                                              float* __restrict__ bias,
                                              __hip_bfloat16* __restrict__ w2t,
                                              __hip_bfloat16* __restrict__ t1p,
                                              float* __restrict__ out,
                                              float* __restrict__ gateL,
                                              float* __restrict__ gateN,
                                              int* __restrict__ kmx) {
  int bx = blockIdx.x;
  int tid = threadIdx.x;
  if (bx == 0 && tid == 0) {
    gateL[0] = 0.f; gateN[0] = 0.f; kmx[0] = 0;
  }
  if (bx < 4488) {
    // ---- xpad[b][66][68][64]: xpad[b][h][w][c] = x[b][(h-2)*64+w][c] or 0 ----
    int pos = bx * 4 + (tid >> 6);
    int c = tid & 63;
    int b = pos / 4488;
    int rem = pos % 4488;
    int h = rem / 68, w = rem % 68;
    int y = h - 2;
    float v = 0.f;
    if (y >= 0 && y < 64 && w < 64 && c < NC)
      v = x[((size_t)b*NN + y*64 + w)*NC + c];
    xp[(size_t)pos*64 + c] = __float2bfloat16(v);
  } else if (bx < 4575) {
    int bw = bx - 4488;
    if (bw < 75) {
      int p = bw / 25, tap = bw % 25, dy = tap / 5, dx = tap % 5;
      for (int i = tid; i < 4096; i += 256) {
        int oc = i >> 6, c = i & 63;
        float v = 0.f;
        if (oc < NC && c < NC) {
          float sc = g[p*NC+oc] * rsqrtf(va[p*NC+oc] + 1e-5f);
          v = w1[(((size_t)p*NC + oc)*NC + c)*25 + tap] * sc;
        }
        int k = dx*64 + c;
        int ks = dy*10 + (k >> 5), ck = k & 31;
        w1t[(((size_t)p*50 + ks)*64 + oc)*32 + ck] = __float2bfloat16(v);
      }
      if (tap == 0 && tid < 64) {
        int oc = tid;
        float v = 0.f;
        if (oc < NC) {
          float sc = g[p*NC+oc] * rsqrtf(va[p*NC+oc] + 1e-5f);
          v = be[p*NC+oc] - mu[p*NC+oc]*sc;
        }
        bias[p*64 + oc] = v;
      }
    } else {
      int i2 = bw - 75;
      int p = i2 / 4, tap = i2 % 4, dy = tap >> 1, dx = tap & 1;
      for (int i = tid; i < 4096; i += 256) {
        int oc = i >> 6, c = i & 63;
        float v = 0.f;
        if (oc < NC && c < NC)
          v = w2[(((size_t)p*NC + oc)*NC + c)*4 + tap];
        int k = dx*64 + c;
        int ks = dy*4 + (k >> 5), ck = k & 31;
        w2t[(((size_t)p*8 + ks)*64 + oc)*32 + ck] = __float2bfloat16(v);
      }
    }
  } else {
    int bz = bx - 4575;
    if (bz < 1536) {
      int idx = bz * 256 + tid;              // 393216 t1pad pad elems
      int pb = idx >> 15, r = idx & 32767;
      int h2, w, c;
      if (r < 16896) {
        int hsel = r / 4224;
        h2 = hsel < 3 ? hsel : 65;
        int rem = r % 4224;
        w = rem >> 6; c = rem & 63;
      } else {
        int r2 = r - 16896;
        h2 = 3 + (r2 >> 8);
        int rem = r2 & 255;
        w = 62 + (rem >> 6); c = rem & 63;
      }
      t1p[(((size_t)pb*66 + h2)*66 + w)*64 + c] = __float2bfloat16(0.f);
    } else {
      int i = (bz - 1536) * 256 + tid;       // 204800 float4 = 819200 f32 of out
      float4 z = {0.f, 0.f, 0.f, 0.f};
      ((float4*)out)[i] = z;
    }
  }
}

// ---------------- C1: conv1 GEMM K=1600; LDS-staged A (once) + W (dbuf/kstep) -----
// grid (62 rows, 12 p*b), 4 waves; wave = 16px x 64oc.  [unchanged from R8]
__global__ __launch_bounds__(256, 3) void k_conv1m(const __hip_bfloat16* __restrict__ xp,
                                                   const __hip_bfloat16* __restrict__ w1t,
                                                   const float* __restrict__ bias,
                                                   __hip_bfloat16* __restrict__ t1p) {
  __shared__ char smem[45056 + 8192];
  char* als = smem;
  char* wls = smem + 45056;
  int tid = threadIdx.x;
  int w = tid >> 6, lane = tid & 63;
  int lr = lane & 15, lk = lane >> 4;
  int row = blockIdx.x;                        // output row 0..61
  int px0 = w * 16;
  int pb = blockIdx.y; int p = pb / 4, b = pb % 4;

  const char* awin = (const char*)xp + (((size_t)b*66 + row)*68) * 128;  // 5 rows x 8704 B
  const char* wsrc = (const char*)w1t + (size_t)p*50*4096;

#pragma unroll
  for (int it = 0; it < 11; ++it) {
    int L = it*4096 + tid*16;
    int PX = L >> 7;
    int slot = ((L >> 4) ^ PX) & 7;
    stage16(awin + PX*128 + slot*16, als + it*4096 + w*1024);
  }
  stage16(wsrc + tid*16, wls + w*1024);
  __syncthreads();                             // vmcnt(0) drain: A + W[0] ready

  f32x4 acc0 = {0.f,0.f,0.f,0.f}, acc1 = acc0, acc2 = acc0, acc3 = acc0;
  int fbase = (px0 + lr)*128 + lk*16;
  const char* wfb = wls + lr*64 + lk*16;

#pragma unroll
  for (int ks = 0; ks < 50; ++ks) {
    if (ks + 1 < 50)                           // async prefetch next W chunk
      stage16(wsrc + (ks+1)*4096 + tid*16, wls + ((ks+1)&1)*4096 + w*1024);
    int dy = ks / 10, kk = ks % 10;
    int F = dy*8704 + fbase + kk*64;           // flat A byte (unswizzled)
    int lb = (F & ~127) | ((((F>>4) ^ (F>>7)) & 7) << 4);
    short8 av = *(const short8*)(als + lb);
    const char* wc = wfb + (ks & 1)*4096;
    short8 wv0 = *(const short8*)(wc);
    short8 wv1 = *(const short8*)(wc + 1024);
    short8 wv2 = *(const short8*)(wc + 2048);
    short8 wv3 = *(const short8*)(wc + 3072);
    acc0 = __builtin_amdgcn_mfma_f32_16x16x32_bf16(av, wv0, acc0, 0, 0, 0);
    acc1 = __builtin_amdgcn_mfma_f32_16x16x32_bf16(av, wv1, acc1, 0, 0, 0);
    acc2 = __builtin_amdgcn_mfma_f32_16x16x32_bf16(av, wv2, acc2, 0, 0, 0);
    acc3 = __builtin_amdgcn_mfma_f32_16x16x32_bf16(av, wv3, acc3, 0, 0, 0);
    __syncthreads();                           // drain prefetch; protect buffer reuse
  }

  int h2 = row + 3;
  __hip_bfloat16* orow = t1p + (((size_t)(p*NB + b)*66 + h2)*66)*64;
  f32x4 accs[4] = {acc0, acc1, acc2, acc3};
#pragma unroll
  for (int nt = 0; nt < 4; ++nt) {
    float bv = bias[p*64 + nt*16 + lr];
#pragma unroll
    for (int r = 0; r < 4; ++r) {
      int j1 = px0 + lk*4 + r;
      float val = (j1 < 62) ? (accs[nt][r] + bv) : 0.f;
      orow[(size_t)j1*64 + nt*16 + lr] = __float2bfloat16(val);
    }
  }
}

// ---------------- C2: conv2 GEMM K=256; A + ALL W staged once, barrier-free loop --
// grid (64 rows, 12 p*b), 4 waves. A = 2 t1p rows; all W staged once. [R8 form]
__global__ __launch_bounds__(256, 3) void k_conv2m(const __hip_bfloat16* __restrict__ t1p,
                                                   const __hip_bfloat16* __restrict__ w2t,
                                                   __hip_bfloat16* __restrict__ qb,
                                                   __hip_bfloat16* __restrict__ kb,
                                                   float* __restrict__ vv,
                                                   float* __restrict__ qn2,
                                                   int* __restrict__ kmx) {
  __shared__ char smem[20480 + 32768];
  char* als = smem;
  char* wls = smem + 20480;
  int tid = threadIdx.x;
  int w = tid >> 6, lane = tid & 63;
  int lr = lane & 15, lk = lane >> 4;
  int row = blockIdx.x;                        // output row 0..63
  int px0 = w * 16;
  int pb = blockIdx.y; int p = pb / 4, b = pb % 4;

  const char* awin = (const char*)t1p + (((size_t)(p*NB + b)*66 + row)*66) * 128; // 2 rows
  const char* wsrc = (const char*)w2t + (size_t)p*8*4096;

#pragma unroll
  for (int it = 0; it < 5; ++it) {
    int L = it*4096 + tid*16;
    int PX = L >> 7;
    int slot = ((L >> 4) ^ PX) & 7;
    stage16(awin + PX*128 + slot*16, als + it*4096 + w*1024);
  }
#pragma unroll
  for (int it = 0; it < 8; ++it)
    stage16(wsrc + it*4096 + tid*16, wls + it*4096 + w*1024);
  __syncthreads();                             // everything resident; no more barriers

  f32x4 acc0 = {0.f,0.f,0.f,0.f}, acc1 = acc0, acc2 = acc0, acc3 = acc0;
  int fbase = (px0 + lr)*128 + lk*16;
  const char* wfb = wls + lr*64 + lk*16;

#pragma unroll
  for (int ks = 0; ks < 8; ++ks) {
    int dy = ks >> 2, kk = ks & 3;
    int F = dy*8448 + fbase + kk*64;
    int lb = (F & ~127) | ((((F>>4) ^ (F>>7)) & 7) << 4);
    short8 av = *(const short8*)(als + lb);
    const char* wc = wfb + ks*4096;
    short8 wv0 = *(const short8*)(wc);
    short8 wv1 = *(const short8*)(wc + 1024);
    short8 wv2 = *(const short8*)(wc + 2048);
    short8 wv3 = *(const short8*)(wc + 3072);
    acc0 = __builtin_amdgcn_mfma_f32_16x16x32_bf16(av, wv0, acc0, 0, 0, 0);
    acc1 = __builtin_amdgcn_mfma_f32_16x16x32_bf16(av, wv1, acc1, 0, 0, 0);
    acc2 = __builtin_amdgcn_mfma_f32_16x16x32_bf16(av, wv2, acc2, 0, 0, 0);
    acc3 = __builtin_amdgcn_mfma_f32_16x16x32_bf16(av, wv3, acc3, 0, 0, 0);
  }

  f32x4 accs[4] = {acc0, acc1, acc2, acc3};
  if (p == 0) {
    float sq[4] = {0.f, 0.f, 0.f, 0.f};
#pragma unroll
    for (int nt = 0; nt < 4; ++nt) {
#pragma unroll
      for (int r = 0; r < 4; ++r) {
        int n = row*64 + px0 + lk*4 + r;
        __hip_bfloat16 qv = __float2bfloat16(accs[nt][r] * (F_SCALE * F_LOG2E));
        qb[((size_t)b*NN + n)*64 + nt*16 + lr] = qv;
        float a = bf2f(*(short*)&qv);
        sq[r] += a*a;
      }
    }
#pragma unroll
    for (int r = 0; r < 4; ++r) {
#pragma unroll
      for (int m = 1; m < 16; m <<= 1) sq[r] += __shfl_xor(sq[r], m, 64);
    }
    if (lr == 0) {
#pragma unroll
      for (int r = 0; r < 4; ++r)
        qn2[(size_t)b*NN + row*64 + px0 + lk*4 + r] = sq[r];
    }
  } else if (p == 1) {
    float sk[4] = {0.f, 0.f, 0.f, 0.f};
#pragma unroll
    for (int nt = 0; nt < 4; ++nt) {
#pragma unroll
      for (int r = 0; r < 4; ++r) {
        int n = row*64 + px0 + lk*4 + r;
        __hip_bfloat16 kv = __float2bfloat16(accs[nt][r]);
        kb[((size_t)b*NN + n)*64 + nt*16 + lr] = kv;
        float a = bf2f(*(short*)&kv);
        sk[r] += a*a;
      }
    }
    float mk = fmaxf(fmaxf(sk[0], sk[1]), fmaxf(sk[2], sk[3]));
#pragma unroll
    for (int m = 1; m < 64; m <<= 1) mk = fmaxf(mk, __shfl_xor(mk, m, 64));
    if (lane == 0) atomicMax(kmx, __float_as_int(mk));  // >=0: bit order == float order
  } else {
#pragma unroll
    for (int nt = 0; nt < 4; ++nt) {
#pragma unroll
      for (int r = 0; r < 4; ++r) {
        int n = row*64 + px0 + lk*4 + r;
        vv[((size_t)b*NN + n)*64 + nt*16 + lr] = accs[nt][r];
      }
    }
  }
}

// ---------------- G2: gateN = sum_t exp2(2*|q~_t|*Kmax)/N  (>= any column mass) ---
__global__ __launch_bounds__(256) void k_gateB(const float* __restrict__ qn2,
                                               const int* __restrict__ kmx,
                                               float* __restrict__ gateN) {
  int i = blockIdx.x * 256 + threadIdx.x;
  float km = sqrtf(__int_as_float(kmx[0]));
  float term = exp2f(2.f * sqrtf(qn2[i]) * km) * (1.f / (float)NN);
  __shared__ float red[256];
  red[threadIdx.x] = term;
  __syncthreads();
  for (int s = 128; s > 0; s >>= 1) {
    if (threadIdx.x < s) red[threadIdx.x] += red[threadIdx.x + s];
    __syncthreads();
  }
  if (threadIdx.x == 0) atomicAdd(gateN, red[0]);
}

// ---------------- K3: MFMA row sums + row max (only if norm gate fails) -----------
__global__ __launch_bounds__(256) void k_L(const __hip_bfloat16* __restrict__ qb,
                                           const __hip_bfloat16* __restrict__ kb,
                                           const float* __restrict__ gateN,
                                           float* __restrict__ Lpart,
                                           float* __restrict__ Mpart) {
  if (F_DT * gateN[0] < 0.99f) return;    // provably no spikes -> L never consumed
  int w = threadIdx.x >> 6, lane = threadIdx.x & 63;
  int b = blockIdx.z, jc = blockIdx.y;
  int t0 = blockIdx.x * 64 + w * 16;
  int lr = lane & 15, lk = lane >> 4;

  const short* qrow = (const short*)qb + ((size_t)b*NN + t0 + lr)*64 + lk*8;
  short8 a0 = *(const short8*)qrow;
  short8 a1 = *(const short8*)(qrow + 32);
  const short* kp = (const short*)kb + ((size_t)b*NN + jc*512 + lr)*64 + lk*8;

  short8 n00 = *(const short8*)kp;
  short8 n01 = *(const short8*)(kp + 32);
  short8 n10 = *(const short8*)(kp + 1024);
  short8 n11 = *(const short8*)(kp + 1024 + 32);

  float rs[4] = {0.f, 0.f, 0.f, 0.f};
  float mx[4] = {-3e38f, -3e38f, -3e38f, -3e38f};
#pragma unroll 2
  for (int j = 0; j < 512; j += 32) {
    short8 b00 = n00, b01 = n01, b10 = n10, b11 = n11;
    kp += 32*64;
    if (j + 32 < 512) {
      n00 = *(const short8*)kp;
      n01 = *(const short8*)(kp + 32);
      n10 = *(const short8*)(kp + 1024);
      n11 = *(const short8*)(kp + 1024 + 32);
    }
    f32x4 d0 = {0.f,0.f,0.f,0.f}, d1 = {0.f,0.f,0.f,0.f};
    d0 = __builtin_amdgcn_mfma_f32_16x16x32_bf16(a0, b00, d0, 0, 0, 0);
    d0 = __builtin_amdgcn_mfma_f32_16x16x32_bf16(a1, b01, d0, 0, 0, 0);
    d1 = __builtin_amdgcn_mfma_f32_16x16x32_bf16(a0, b10, d1, 0, 0, 0);
    d1 = __builtin_amdgcn_mfma_f32_16x16x32_bf16(a1, b11, d1, 0, 0, 0);
#pragma unroll
    for (int r = 0; r < 4; ++r) {
      rs[r] += exp2f(d0[r]) + exp2f(d1[r]);
      mx[r] = fmaxf(mx[r], fmaxf(d0[r], d1[r]));
    }
  }
#pragma unroll
  for (int r = 0; r < 4; ++r) {
#pragma unroll
    for (int m = 1; m < 16; m <<= 1) {
      rs[r] += __shfl_xor(rs[r], m, 64);
      mx[r] = fmaxf(mx[r], __shfl_xor(mx[r], m, 64));
    }
  }
  if (lr == 0) {
    size_t base = (size_t)jc*(NB*NN) + (size_t)b*NN + t0 + lk*4;
#pragma unroll
    for (int r = 0; r < 4; ++r) {
      Lpart[base + r] = rs[r];
      Mpart[base + r] = mx[r];
    }
  }
}

// ---------------- K3b: reduce L, M; gateL = sum_t exp2(M_t)/L_t -------------------
__global__ __launch_bounds__(256) void k_Lred(const float* __restrict__ Lpart,
                                              const float* __restrict__ Mpart,
                                              const float* __restrict__ gateN,
                                              float* __restrict__ L,
                                              float* __restrict__ gateL) {
  if (F_DT * gateN[0] < 0.99f) return;
  int i = blockIdx.x * 256 + threadIdx.x;   // 16384
  float sum = 0.f, mx = -3e38f;
#pragma unroll
  for (int jc = 0; jc < 8; ++jc) {
    sum += Lpart[(size_t)jc*(NB*NN) + i];
    mx = fmaxf(mx, Mpart[(size_t)jc*(NB*NN) + i]);
  }
  L[i] = sum;
  float m = exp2f(mx) / sum;
  __shared__ float red[256];
  red[threadIdx.x] = m;
  __syncthreads();
  for (int s = 128; s > 0; s >>= 1) {
    if (threadIdx.x < s) red[threadIdx.x] += red[threadIdx.x + s];
    __syncthreads();
  }
  if (threadIdx.x == 0) atomicAdd(gateL, red[0]);
}

// ---------------- K5: spike fallback (exact serial walk; doubly gated) ------------
__global__ __launch_bounds__(256) void k_spike_fb(const __hip_bfloat16* __restrict__ qb,
                                                  const __hip_bfloat16* __restrict__ kb,
                                                  const float* __restrict__ L,
                                                  const float* __restrict__ gateN,
                                                  const float* __restrict__ gateL,
                                                  const float* __restrict__ vv,
                                                  float* __restrict__ out) {
  if (F_DT * gateN[0] < 0.99f) return;    // cheap bound says no spikes
  if (F_DT * gateL[0] < 0.99f) return;    // tight bound says no spikes
  int j = blockIdx.x * 256 + threadIdx.x;
  int b = blockIdx.y;

  float kf[64];
  const __hip_bfloat16* kr = kb + ((size_t)b*NN + j)*64;
#pragma unroll
  for (int c = 0; c < 64; ++c) kf[c] = __bfloat162float(kr[c]);
  const __hip_bfloat16* Qb = qb + (size_t)b*NN*64;
  const float* Lb = L + (size_t)b*NN;
  const float* V  = vv + ((size_t)b*NN + j)*64;

  float cum = 0.f, Fprev = 0.f;
  for (int t = 0; t < NN; ++t) {
    const __hip_bfloat16* qr = Qb + (size_t)t*64;
    float dot = 0.f;
    for (int c = 0; c < 64; ++c) dot += __bfloat162float(qr[c]) * kf[c];
    float r = exp2f(dot) / Lb[t];
    cum += r * F_DT;
    float F = floorf(cum);
    if (F > Fprev) {
      float sv = (F - Fprev) / F_DT;
      float* orow = out + ((size_t)b*NN + t)*NC;
      for (int d = 0; d < NC; ++d) atomicAdd(orow + d, sv * V[d]);
      Fprev = F;
    }
  }
}

extern "C" void kernel_launch(void* const* d_in, const int* in_sizes, int n_in,
                              void* d_out, int out_size, void* d_ws, size_t ws_size,
                              hipStream_t stream) {
  const float* x  = (const float*)d_in[0];
  const float* w1 = (const float*)d_in[1];
  const float* w2 = (const float*)d_in[2];
  const float* g  = (const float*)d_in[3];
  const float* be = (const float*)d_in[4];
  const float* mu = (const float*)d_in[5];
  const float* va = (const float*)d_in[6];
  float* out = (float*)d_out;
  float* ws  = (float*)d_ws;

  __hip_bfloat16* xp  = (__hip_bfloat16*)(ws + OFF_XP);
  __hip_bfloat16* w1t = (__hip_bfloat16*)(ws + OFF_W1T);
  float*          bi  = ws + OFF_BI;
  __hip_bfloat16* w2t = (__hip_bfloat16*)(ws + OFF_W2T);
  __hip_bfloat16* t1p = (__hip_bfloat16*)(ws + OFF_T1P);
  __hip_bfloat16* qb  = (__hip_bfloat16*)(ws + OFF_QB);
  __hip_bfloat16* kb  = (__hip_bfloat16*)(ws + OFF_KB);
  float* vv  = ws + OFF_VV;
  float* Lp  = ws + OFF_LP;
  float* Mp  = ws + OFF_MP;
  float* L   = ws + OFF_L;
  float* gtL = ws + OFF_GT;
  float* qn2 = ws + OFF_QN2;
  int*   kmx = (int*)(ws + OFF_KMX);
  float* gtN = ws + OFF_GN;

  k_prep  <<<dim3(6911), dim3(256), 0, stream>>>(x, w1, w2, g, be, mu, va,
                                                 xp, w1t, bi, w2t, t1p, out,
                                                 gtL, gtN, kmx);
  k_conv1m<<<dim3(62, 12), dim3(256), 0, stream>>>(xp, w1t, bi, t1p);
  k_conv2m<<<dim3(64, 12), dim3(256), 0, stream>>>(t1p, w2t, qb, kb, vv, qn2, kmx);
  k_gateB <<<dim3(64), dim3(256), 0, stream>>>(qn2, kmx, gtN);
  k_L     <<<dim3(64, 8, NB), dim3(256), 0, stream>>>(qb, kb, gtN, Lp, Mp);
  k_Lred  <<<dim3(64), dim3(256), 0, stream>>>(Lp, Mp, gtN, L, gtL);
  k_spike_fb<<<dim3(16, NB), dim3(256), 0, stream>>>(qb, kb, L, gtN, gtL, vv, out);
}

// Round 11
// 53.071 us; speedup vs baseline: 2.4806x; 1.1215x over previous
//
#include <hip/hip_runtime.h>
#include <hip/hip_bf16.h>
#include <math.h>

#define NB 4
#define NC 50
#define NN 4096

typedef __attribute__((ext_vector_type(8))) short short8;
typedef __attribute__((ext_vector_type(4))) float f32x4;

static constexpr float F_SCALE = 0.14142135623730951f;  // 50^-0.5
static constexpr float F_LOG2E = 1.44269504088896340f;  // exp(x)=exp2(x*log2e), folded into qb
static constexpr float F_DT = 0.001f;

// ---- workspace layout (f32 units) ----
static constexpr size_t OFF_XP  = 0;                                   // xpad [4][66][68][64] bf16
static constexpr size_t SZ_XP   = (size_t)4*66*68*64/2;
static constexpr size_t OFF_W1T = OFF_XP + SZ_XP;                      // w1t2 [3][50ks][64oc][32] bf16
static constexpr size_t SZ_W1T  = (size_t)3*25*64*64/2;
static constexpr size_t OFF_BI  = OFF_W1T + SZ_W1T;                    // bias [3][64] f32
static constexpr size_t SZ_BI   = 192;
static constexpr size_t OFF_W2T = OFF_BI + SZ_BI;                      // w2t2 [3][8ks][64oc][32] bf16
static constexpr size_t SZ_W2T  = (size_t)3*4*64*64/2;
static constexpr size_t OFF_T1P = OFF_W2T + SZ_W2T;                    // t1pad [12][66][66][64] bf16
static constexpr size_t SZ_T1P  = (size_t)12*66*66*64/2;
static constexpr size_t OFF_QB  = OFF_T1P + SZ_T1P;                    // qb [4][4096][64] bf16 (scaled*log2e)
static constexpr size_t SZ_QB   = (size_t)4*NN*64/2;
static constexpr size_t OFF_KB  = OFF_QB + SZ_QB;
static constexpr size_t SZ_KB   = SZ_QB;
static constexpr size_t OFF_VV  = OFF_KB + SZ_KB;                      // vv [4][4096][64] f32
static constexpr size_t SZ_VV   = (size_t)4*NN*64;
static constexpr size_t OFF_LP  = OFF_VV + SZ_VV;                      // Lpart [8][16384]
static constexpr size_t SZ_LP   = (size_t)8*NB*NN;
static constexpr size_t OFF_MP  = OFF_LP + SZ_LP;                      // Mpart [8][16384]
static constexpr size_t SZ_MP   = (size_t)8*NB*NN;
static constexpr size_t OFF_GT  = OFF_MP + SZ_MP;                      // gateL [1] (legacy init)
static constexpr size_t OFF_QN2 = OFF_GT + 1;                          // qnorm2 [16384]
static constexpr size_t SZ_QN2  = (size_t)NB*NN;
static constexpr size_t OFF_KMX = OFF_QN2 + SZ_QN2;                    // kmax2 bits [1]
static constexpr size_t OFF_GN  = OFF_KMX + 1;                         // gateN [1]

__device__ __forceinline__ float bf2f(short s) {
  return __uint_as_float(((unsigned)(unsigned short)s) << 16);
}

// async global->LDS DMA, 16B per lane; LDS dest = wave-uniform base + lane*16,
// global source is per-lane. (m97 mechanism: compiler can't sink past barrier.)
__device__ __forceinline__ void stage16(const void* g, void* l) {
  __builtin_amdgcn_global_load_lds(
      (const __attribute__((address_space(1))) unsigned*)g,
      (__attribute__((address_space(3))) unsigned*)l, 16, 0, 0);
}

// ---------------- P: merged prep — xpad build + weight prep + init (one dispatch) --
__global__ __launch_bounds__(256) void k_prep(const float* __restrict__ x,
                                              const float* __restrict__ w1,
                                              const float* __restrict__ w2,
                                              const float* __restrict__ g,
                                              const float* __restrict__ be,
                                              const float* __restrict__ mu,
                                              const float* __restrict__ va,
                                              __hip_bfloat16* __restrict__ xp,
                                              __hip_bfloat16* __restrict__ w1t,
                                              float* __restrict__ bias,
                                              __hip_bfloat16* __restrict__ w2t,
                                              __hip_bfloat16* __restrict__ t1p,
                                              float* __restrict__ out,
                                              float* __restrict__ gateL,
                                              float* __restrict__ gateN,
                                              int* __restrict__ kmx) {
  int bx = blockIdx.x;
  int tid = threadIdx.x;
  if (bx == 0 && tid == 0) {
    gateL[0] = 0.f; gateN[0] = 0.f; kmx[0] = 0;
  }
  if (bx < 4488) {
    int pos = bx * 4 + (tid >> 6);
    int c = tid & 63;
    int b = pos / 4488;
    int rem = pos % 4488;
    int h = rem / 68, w = rem % 68;
    int y = h - 2;
    float v = 0.f;
    if (y >= 0 && y < 64 && w < 64 && c < NC)
      v = x[((size_t)b*NN + y*64 + w)*NC + c];
    xp[(size_t)pos*64 + c] = __float2bfloat16(v);
  } else if (bx < 4575) {
    int bw = bx - 4488;
    if (bw < 75) {
      int p = bw / 25, tap = bw % 25, dy = tap / 5, dx = tap % 5;
      for (int i = tid; i < 4096; i += 256) {
        int oc = i >> 6, c = i & 63;
        float v = 0.f;
        if (oc < NC && c < NC) {
          float sc = g[p*NC+oc] * rsqrtf(va[p*NC+oc] + 1e-5f);
          v = w1[(((size_t)p*NC + oc)*NC + c)*25 + tap] * sc;
        }
        int k = dx*64 + c;
        int ks = dy*10 + (k >> 5), ck = k & 31;
        w1t[(((size_t)p*50 + ks)*64 + oc)*32 + ck] = __float2bfloat16(v);
      }
      if (tap == 0 && tid < 64) {
        int oc = tid;
        float v = 0.f;
        if (oc < NC) {
          float sc = g[p*NC+oc] * rsqrtf(va[p*NC+oc] + 1e-5f);
          v = be[p*NC+oc] - mu[p*NC+oc]*sc;
        }
        bias[p*64 + oc] = v;
      }
    } else {
      int i2 = bw - 75;
      int p = i2 / 4, tap = i2 % 4, dy = tap >> 1, dx = tap & 1;
      for (int i = tid; i < 4096; i += 256) {
        int oc = i >> 6, c = i & 63;
        float v = 0.f;
        if (oc < NC && c < NC)
          v = w2[(((size_t)p*NC + oc)*NC + c)*4 + tap];
        int k = dx*64 + c;
        int ks = dy*4 + (k >> 5), ck = k & 31;
        w2t[(((size_t)p*8 + ks)*64 + oc)*32 + ck] = __float2bfloat16(v);
      }
    }
  } else {
    int bz = bx - 4575;
    if (bz < 1536) {
      int idx = bz * 256 + tid;              // 393216 t1pad pad elems
      int pb = idx >> 15, r = idx & 32767;
      int h2, w, c;
      if (r < 16896) {
        int hsel = r / 4224;
        h2 = hsel < 3 ? hsel : 65;
        int rem = r % 4224;
        w = rem >> 6; c = rem & 63;
      } else {
        int r2 = r - 16896;
        h2 = 3 + (r2 >> 8);
        int rem = r2 & 255;
        w = 62 + (rem >> 6); c = rem & 63;
      }
      t1p[(((size_t)pb*66 + h2)*66 + w)*64 + c] = __float2bfloat16(0.f);
    } else {
      int i = (bz - 1536) * 256 + tid;       // 204800 float4 = 819200 f32 of out
      float4 z = {0.f, 0.f, 0.f, 0.f};
      ((float4*)out)[i] = z;
    }
  }
}

// ---------------- C1: conv1 GEMM K=1600; oc-split waves, barrier-free K-loop ------
// grid (62 rows, 12 p*b), 4 waves; wave w = oc [w*16,w*16+16) x 64 px.
// A (45KB) staged once, shared, XOR-swizzled (source-permuted, read-matched).
// W: per-wave PRIVATE 2x1KB double buffer, staged via stage16 with counted
// s_waitcnt vmcnt(1) — no __syncthreads in the 50-kstep loop (vmcnt is per-wave,
// buffers private, A read-only after the single initial barrier).
__global__ __launch_bounds__(256, 3) void k_conv1m(const __hip_bfloat16* __restrict__ xp,
                                                   const __hip_bfloat16* __restrict__ w1t,
                                                   const float* __restrict__ bias,
                                                   __hip_bfloat16* __restrict__ t1p) {
  __shared__ char smem[45056 + 8192];
  char* als = smem;
  char* wls = smem + 45056;
  int tid = threadIdx.x;
  int w = tid >> 6, lane = tid & 63;
  int lr = lane & 15, lk = lane >> 4;
  int row = blockIdx.x;                        // output row 0..61
  int pb = blockIdx.y; int p = pb / 4, b = pb % 4;

  const char* awin = (const char*)xp + (((size_t)b*66 + row)*68) * 128;  // 5 rows x 8704 B
  const char* wsrc = (const char*)w1t + (size_t)p*50*4096 + w*1024;      // wave's oc chunk
  // W source permutation: physical slot (oc_local=lane>>2, s=lane&3) pulls logical
  // slot s ^ ((oc_local>>1)&3)  ->  read-side XOR spreads 16 lanes over 8 banks (2-way, free)
  int lanebyte = (lane >> 2)*64 + (((lane & 3) ^ ((lane >> 3) & 3)))*16;
  char* wbuf = wls + w*2048;                   // private 2x1KB dbuf

  // ---- stage A window (shared, swizzled source) + W[0] (private) ----
#pragma unroll
  for (int it = 0; it < 11; ++it) {
    int L = it*4096 + tid*16;
    int PX = L >> 7;
    int slot = ((L >> 4) ^ PX) & 7;
    stage16(awin + PX*128 + slot*16, als + it*4096 + w*1024);
  }
  stage16(wsrc + lanebyte, wbuf);
  float bv = bias[p*64 + w*16 + lr];           // load BEFORE barrier: keeps K-loop
  asm volatile("" :: "v"(bv));                 // free of stray VMEM (vmcnt counting)
  __syncthreads();                             // drains everything to vmcnt(0)

  f32x4 acc0 = {0.f,0.f,0.f,0.f}, acc1 = acc0, acc2 = acc0, acc3 = acc0;
  const char* wrd = wbuf + lr*64 + ((lk ^ ((lr >> 1) & 3)))*16;
  int fb = lr*128 + lk*16;

#pragma unroll
  for (int ks = 0; ks < 50; ++ks) {
    if (ks + 1 < 50) {
      stage16(wsrc + (ks+1)*4096 + lanebyte, wbuf + ((ks+1)&1)*1024);
      asm volatile("s_waitcnt vmcnt(1)" ::: "memory");   // retire W[ks], keep W[ks+1] in flight
    } else {
      asm volatile("s_waitcnt vmcnt(0)" ::: "memory");
    }
    __builtin_amdgcn_sched_barrier(0);         // rule #18: no hoisting above the wait
    int dy = ks / 10, kk = ks % 10;
    short8 wv = *(const short8*)(wrd + (ks & 1)*1024);
    int F0 = dy*8704 + kk*64 + fb;
#pragma unroll
    for (int t = 0; t < 4; ++t) {
      int F = F0 + t*2048;                     // +16 px per tile
      int lb = (F & ~127) | ((((F >> 4) ^ (F >> 7)) & 7) << 4);
      short8 av = *(const short8*)(als + lb);
      f32x4* ac = (t == 0) ? &acc0 : (t == 1) ? &acc1 : (t == 2) ? &acc2 : &acc3;
      *ac = __builtin_amdgcn_mfma_f32_16x16x32_bf16(av, wv, *ac, 0, 0, 0);
    }
  }

  // D: row = px-local (lk*4+r) within tile t, col = oc-local lr
  int h2 = row + 3;
  __hip_bfloat16* orow = t1p + (((size_t)(p*NB + b)*66 + h2)*66)*64;
  f32x4 accs[4] = {acc0, acc1, acc2, acc3};
#pragma unroll
  for (int t = 0; t < 4; ++t) {
#pragma unroll
    for (int r = 0; r < 4; ++r) {
      int j1 = t*16 + lk*4 + r;
      float val = (j1 < 62) ? (accs[t][r] + bv) : 0.f;
      orow[(size_t)j1*64 + w*16 + lr] = __float2bfloat16(val);
    }
  }
}

// ---------------- C2: conv2 GEMM K=256; A + ALL W staged once, barrier-free loop --
// [R10 form, unchanged — it already has no in-loop barriers]
__global__ __launch_bounds__(256, 3) void k_conv2m(const __hip_bfloat16* __restrict__ t1p,
                                                   const __hip_bfloat16* __restrict__ w2t,
                                                   __hip_bfloat16* __restrict__ qb,
                                                   __hip_bfloat16* __restrict__ kb,
                                                   float* __restrict__ vv,
                                                   float* __restrict__ qn2,
                                                   int* __restrict__ kmx) {
  __shared__ char smem[20480 + 32768];
  char* als = smem;
  char* wls = smem + 20480;
  int tid = threadIdx.x;
  int w = tid >> 6, lane = tid & 63;
  int lr = lane & 15, lk = lane >> 4;
  int row = blockIdx.x;                        // output row 0..63
  int px0 = w * 16;
  int pb = blockIdx.y; int p = pb / 4, b = pb % 4;

  const char* awin = (const char*)t1p + (((size_t)(p*NB + b)*66 + row)*66) * 128; // 2 rows
  const char* wsrc = (const char*)w2t + (size_t)p*8*4096;

#pragma unroll
  for (int it = 0; it < 5; ++it) {
    int L = it*4096 + tid*16;
    int PX = L >> 7;
    int slot = ((L >> 4) ^ PX) & 7;
    stage16(awin + PX*128 + slot*16, als + it*4096 + w*1024);
  }
#pragma unroll
  for (int it = 0; it < 8; ++it)
    stage16(wsrc + it*4096 + tid*16, wls + it*4096 + w*1024);
  __syncthreads();                             // everything resident; no more barriers

  f32x4 acc0 = {0.f,0.f,0.f,0.f}, acc1 = acc0, acc2 = acc0, acc3 = acc0;
  int fbase = (px0 + lr)*128 + lk*16;
  const char* wfb = wls + lr*64 + lk*16;

#pragma unroll
  for (int ks = 0; ks < 8; ++ks) {
    int dy = ks >> 2, kk = ks & 3;
    int F = dy*8448 + fbase + kk*64;
    int lb = (F & ~127) | ((((F>>4) ^ (F>>7)) & 7) << 4);
    short8 av = *(const short8*)(als + lb);
    const char* wc = wfb + ks*4096;
    short8 wv0 = *(const short8*)(wc);
    short8 wv1 = *(const short8*)(wc + 1024);
    short8 wv2 = *(const short8*)(wc + 2048);
    short8 wv3 = *(const short8*)(wc + 3072);
    acc0 = __builtin_amdgcn_mfma_f32_16x16x32_bf16(av, wv0, acc0, 0, 0, 0);
    acc1 = __builtin_amdgcn_mfma_f32_16x16x32_bf16(av, wv1, acc1, 0, 0, 0);
    acc2 = __builtin_amdgcn_mfma_f32_16x16x32_bf16(av, wv2, acc2, 0, 0, 0);
    acc3 = __builtin_amdgcn_mfma_f32_16x16x32_bf16(av, wv3, acc3, 0, 0, 0);
  }

  f32x4 accs[4] = {acc0, acc1, acc2, acc3};
  if (p == 0) {
    float sq[4] = {0.f, 0.f, 0.f, 0.f};
#pragma unroll
    for (int nt = 0; nt < 4; ++nt) {
#pragma unroll
      for (int r = 0; r < 4; ++r) {
        int n = row*64 + px0 + lk*4 + r;
        __hip_bfloat16 qv = __float2bfloat16(accs[nt][r] * (F_SCALE * F_LOG2E));
        qb[((size_t)b*NN + n)*64 + nt*16 + lr] = qv;
        float a = bf2f(*(short*)&qv);
        sq[r] += a*a;
      }
    }
#pragma unroll
    for (int r = 0; r < 4; ++r) {
#pragma unroll
      for (int m = 1; m < 16; m <<= 1) sq[r] += __shfl_xor(sq[r], m, 64);
    }
    if (lr == 0) {
#pragma unroll
      for (int r = 0; r < 4; ++r)
        qn2[(size_t)b*NN + row*64 + px0 + lk*4 + r] = sq[r];
    }
  } else if (p == 1) {
    float sk[4] = {0.f, 0.f, 0.f, 0.f};
#pragma unroll
    for (int nt = 0; nt < 4; ++nt) {
#pragma unroll
      for (int r = 0; r < 4; ++r) {
        int n = row*64 + px0 + lk*4 + r;
        __hip_bfloat16 kv = __float2bfloat16(accs[nt][r]);
        kb[((size_t)b*NN + n)*64 + nt*16 + lr] = kv;
        float a = bf2f(*(short*)&kv);
        sk[r] += a*a;
      }
    }
    float mk = fmaxf(fmaxf(sk[0], sk[1]), fmaxf(sk[2], sk[3]));
#pragma unroll
    for (int m = 1; m < 64; m <<= 1) mk = fmaxf(mk, __shfl_xor(mk, m, 64));
    if (lane == 0) atomicMax(kmx, __float_as_int(mk));  // >=0: bit order == float order
  } else {
#pragma unroll
    for (int nt = 0; nt < 4; ++nt) {
#pragma unroll
      for (int r = 0; r < 4; ++r) {
        int n = row*64 + px0 + lk*4 + r;
        vv[((size_t)b*NN + n)*64 + nt*16 + lr] = accs[nt][r];
      }
    }
  }
}

// ---------------- G2: gateN = sum_t exp2(2*|q~_t|*Kmax)/N  (>= any column mass) ---
__global__ __launch_bounds__(256) void k_gateB(const float* __restrict__ qn2,
                                               const int* __restrict__ kmx,
                                               float* __restrict__ gateN) {
  int i = blockIdx.x * 256 + threadIdx.x;
  float km = sqrtf(__int_as_float(kmx[0]));
  float term = exp2f(2.f * sqrtf(qn2[i]) * km) * (1.f / (float)NN);
  __shared__ float red[256];
  red[threadIdx.x] = term;
  __syncthreads();
  for (int s = 128; s > 0; s >>= 1) {
    if (threadIdx.x < s) red[threadIdx.x] += red[threadIdx.x + s];
    __syncthreads();
  }
  if (threadIdx.x == 0) atomicAdd(gateN, red[0]);
}

// ---------------- K3: MFMA row sums + row max (only if norm gate fails) -----------
__global__ __launch_bounds__(256) void k_L(const __hip_bfloat16* __restrict__ qb,
                                           const __hip_bfloat16* __restrict__ kb,
                                           const float* __restrict__ gateN,
                                           float* __restrict__ Lpart,
                                           float* __restrict__ Mpart) {
  if (F_DT * gateN[0] < 0.99f) return;    // provably no spikes -> L never consumed
  int w = threadIdx.x >> 6, lane = threadIdx.x & 63;
  int b = blockIdx.z, jc = blockIdx.y;
  int t0 = blockIdx.x * 64 + w * 16;
  int lr = lane & 15, lk = lane >> 4;

  const short* qrow = (const short*)qb + ((size_t)b*NN + t0 + lr)*64 + lk*8;
  short8 a0 = *(const short8*)qrow;
  short8 a1 = *(const short8*)(qrow + 32);
  const short* kp = (const short*)kb + ((size_t)b*NN + jc*512 + lr)*64 + lk*8;

  short8 n00 = *(const short8*)kp;
  short8 n01 = *(const short8*)(kp + 32);
  short8 n10 = *(const short8*)(kp + 1024);
  short8 n11 = *(const short8*)(kp + 1024 + 32);

  float rs[4] = {0.f, 0.f, 0.f, 0.f};
  float mx[4] = {-3e38f, -3e38f, -3e38f, -3e38f};
#pragma unroll 2
  for (int j = 0; j < 512; j += 32) {
    short8 b00 = n00, b01 = n01, b10 = n10, b11 = n11;
    kp += 32*64;
    if (j + 32 < 512) {
      n00 = *(const short8*)kp;
      n01 = *(const short8*)(kp + 32);
      n10 = *(const short8*)(kp + 1024);
      n11 = *(const short8*)(kp + 1024 + 32);
    }
    f32x4 d0 = {0.f,0.f,0.f,0.f}, d1 = {0.f,0.f,0.f,0.f};
    d0 = __builtin_amdgcn_mfma_f32_16x16x32_bf16(a0, b00, d0, 0, 0, 0);
    d0 = __builtin_amdgcn_mfma_f32_16x16x32_bf16(a1, b01, d0, 0, 0, 0);
    d1 = __builtin_amdgcn_mfma_f32_16x16x32_bf16(a0, b10, d1, 0, 0, 0);
    d1 = __builtin_amdgcn_mfma_f32_16x16x32_bf16(a1, b11, d1, 0, 0, 0);
#pragma unroll
    for (int r = 0; r < 4; ++r) {
      rs[r] += exp2f(d0[r]) + exp2f(d1[r]);
      mx[r] = fmaxf(mx[r], fmaxf(d0[r], d1[r]));
    }
  }
#pragma unroll
  for (int r = 0; r < 4; ++r) {
#pragma unroll
    for (int m = 1; m < 16; m <<= 1) {
      rs[r] += __shfl_xor(rs[r], m, 64);
      mx[r] = fmaxf(mx[r], __shfl_xor(mx[r], m, 64));
    }
  }
  if (lr == 0) {
    size_t base = (size_t)jc*(NB*NN) + (size_t)b*NN + t0 + lk*4;
#pragma unroll
    for (int r = 0; r < 4; ++r) {
      Lpart[base + r] = rs[r];
      Mpart[base + r] = mx[r];
    }
  }
}

// ---------------- K5: spike fallback — merged Lred + exact serial walk ------------
// Gated by gateN. If it ever fails: each block rebuilds its batch's L[4096] from
// Lpart into LDS, computes the per-batch gateL = sum_t exp2(M_t)/L_t (sound upper
// bound on any column mass within the batch), and only walks if that also fails.
__global__ __launch_bounds__(256) void k_spike_fb(const __hip_bfloat16* __restrict__ qb,
                                                  const __hip_bfloat16* __restrict__ kb,
                                                  const float* __restrict__ Lpart,
                                                  const float* __restrict__ Mpart,
                                                  const float* __restrict__ gateN,
                                                  const float* __restrict__ vv,
                                                  float* __restrict__ out) {
  if (F_DT * gateN[0] < 0.99f) return;    // cheap bound says no spikes
  int tid = threadIdx.x;
  int b = blockIdx.y;

  __shared__ float Ls[NN];
  __shared__ float red[256];
  float gpart = 0.f;
  for (int t = tid; t < NN; t += 256) {
    float sum = 0.f, mx = -3e38f;
#pragma unroll
    for (int jc = 0; jc < 8; ++jc) {
      sum += Lpart[(size_t)jc*(NB*NN) + (size_t)b*NN + t];
      mx = fmaxf(mx, Mpart[(size_t)jc*(NB*NN) + (size_t)b*NN + t]);
    }
    Ls[t] = sum;
    gpart += exp2f(mx) / sum;
  }
  red[tid] = gpart;
  __syncthreads();
  for (int s = 128; s > 0; s >>= 1) {
    if (tid < s) red[tid] += red[tid + s];
    __syncthreads();
  }
  if (F_DT * red[0] < 0.99f) return;      // tight per-batch bound says no spikes

  int j = blockIdx.x * 256 + tid;
  float kf[64];
  const __hip_bfloat16* kr = kb + ((size_t)b*NN + j)*64;
#pragma unroll
  for (int c = 0; c < 64; ++c) kf[c] = __bfloat162float(kr[c]);
  const __hip_bfloat16* Qb = qb + (size_t)b*NN*64;
  const float* V  = vv + ((size_t)b*NN + j)*64;

  float cum = 0.f, Fprev = 0.f;
  for (int t = 0; t < NN; ++t) {
    const __hip_bfloat16* qr = Qb + (size_t)t*64;
    float dot = 0.f;
    for (int c = 0; c < 64; ++c) dot += __bfloat162float(qr[c]) * kf[c];
    float r = exp2f(dot) / Ls[t];
    cum += r * F_DT;
    float F = floorf(cum);
    if (F > Fprev) {
      float sv = (F - Fprev) / F_DT;
      float* orow = out + ((size_t)b*NN + t)*NC;
      for (int d = 0; d < NC; ++d) atomicAdd(orow + d, sv * V[d]);
      Fprev = F;
    }
  }
}

extern "C" void kernel_launch(void* const* d_in, const int* in_sizes, int n_in,
                              void* d_out, int out_size, void* d_ws, size_t ws_size,
                              hipStream_t stream) {
  const float* x  = (const float*)d_in[0];
  const float* w1 = (const float*)d_in[1];
  const float* w2 = (const float*)d_in[2];
  const float* g  = (const float*)d_in[3];
  const float* be = (const float*)d_in[4];
  const float* mu = (const float*)d_in[5];
  const float* va = (const float*)d_in[6];
  float* out = (float*)d_out;
  float* ws  = (float*)d_ws;

  __hip_bfloat16* xp  = (__hip_bfloat16*)(ws + OFF_XP);
  __hip_bfloat16* w1t = (__hip_bfloat16*)(ws + OFF_W1T);
  float*          bi  = ws + OFF_BI;
  __hip_bfloat16* w2t = (__hip_bfloat16*)(ws + OFF_W2T);
  __hip_bfloat16* t1p = (__hip_bfloat16*)(ws + OFF_T1P);
  __hip_bfloat16* qb  = (__hip_bfloat16*)(ws + OFF_QB);
  __hip_bfloat16* kb  = (__hip_bfloat16*)(ws + OFF_KB);
  float* vv  = ws + OFF_VV;
  float* Lp  = ws + OFF_LP;
  float* Mp  = ws + OFF_MP;
  float* gtL = ws + OFF_GT;
  float* qn2 = ws + OFF_QN2;
  int*   kmx = (int*)(ws + OFF_KMX);
  float* gtN = ws + OFF_GN;

  k_prep  <<<dim3(6911), dim3(256), 0, stream>>>(x, w1, w2, g, be, mu, va,
                                                 xp, w1t, bi, w2t, t1p, out,
                                                 gtL, gtN, kmx);
  k_conv1m<<<dim3(62, 12), dim3(256), 0, stream>>>(xp, w1t, bi, t1p);
  k_conv2m<<<dim3(64, 12), dim3(256), 0, stream>>>(t1p, w2t, qb, kb, vv, qn2, kmx);
  k_gateB <<<dim3(64), dim3(256), 0, stream>>>(qn2, kmx, gtN);
  k_L     <<<dim3(64, 8, NB), dim3(256), 0, stream>>>(qb, kb, gtN, Lp, Mp);
  k_spike_fb<<<dim3(16, NB), dim3(256), 0, stream>>>(qb, kb, Lp, Mp, gtN, vv, out);
}